// Round 3
// baseline (163.673 us; speedup 1.0000x reference)
//
#include <hip/hip_runtime.h>

// NeuSSampler PDF importance resampling — v3: TWO rays per wave.
// (Resubmission: previous round's bench failed with "MI355X container failed
// twice" — broker/infra failure, no kernel error. Kernel audited: all loops
// bounded, no barriers, unaligned loads proven OK on this HW by v1/v2.)
//
// Post-mortem of v2: removing the divergent interp bodies didn't move time
// (50us -> 50us). Counter math: ~197 wave64 VALU instructions per ray, each
// wave-wide instruction serving ONE ray => issue-bound on per-ray fixed
// overhead (scan, edges, jf, loop control, prologue/epilogue). v3 packs 2
// rays per wave (32 lanes/ray, 4 weights+bins per lane via float4), so every
// wave64 instruction serves 2 rays:
//   - scan: 5 DPP adds (row_shr:1/2/4/8 + row_bcast:15 rmask 0xa) give two
//     independent 32-lane inclusive scans (skip row_bcast:31)
//   - per-lane 4 segments; edges e[0..4], slot ranges J[0..4] tile [0,65)
//     per ray-half exactly (shared edges move across lanes only via shfl,
//     never recomputed; integer clamps force monotone tiling)
//   - scatter: loop-invariant 16B payload {c_start, rcp(d),
//     fmaf(b0,fmn,near), bd*fmn} per covered slot into wave-private LDS;
//     uniform epilogue reads slot j, interps, coalesced 256B row stores.
//
// Degenerate cases: duplicate cdf entries -> empty segment (clamped J);
// d==0 with nonempty range -> rcp(0)=inf -> t=+/-inf/NaN -> fmaxf(NaN,0)=0 /
// fminf(inf,1)=1, matching reference nan_to_num + clip gather semantics.

#define DPP_FADD(x, ctrl, rmask)                                             \
    ((x) + __int_as_float(__builtin_amdgcn_update_dpp(                       \
               0, __float_as_int(x), (ctrl), (rmask), 0xf, true)))

__global__ __launch_bounds__(256) void neus_sampler_kernel(
    const float* __restrict__ weights,
    const float* __restrict__ bins_g,
    const float* __restrict__ nears,
    const float* __restrict__ fars,
    float* __restrict__ out,
    int R)
{
    constexpr int S  = 128;   // weights per ray
    constexpr int NB = 65;    // output samples per ray
    constexpr float HPAD = 1e-5f;

    __shared__ float4 pay[4][2][NB];            // 8320 B/block, wave-private

    const int lane = threadIdx.x & 63;
    const int wv   = threadIdx.x >> 6;
    const int q    = lane & 31;                 // lane within ray-half
    const int h    = lane >> 5;                 // which ray of the pair
    const int ray0 = (blockIdx.x * 4 + wv) * 2; // first ray of this wave
    if (ray0 >= R) return;                      // wave-uniform
    const int uray = __builtin_amdgcn_readfirstlane(ray0);
    const int rayB = (uray + 1 < R) ? uray + 1 : uray;   // clamp (R even here)
    const bool haveB = (uray + 1 < R);

    // ---- coalesced float4 loads: 4 weights + 4 bin edges per lane ----
    // weights row = 512B (16B aligned); wave covers 1024B contiguous.
    const float4 wq = *reinterpret_cast<const float4*>(
        weights + (size_t)uray * S + (size_t)(h ? (rayB - uray) : 0) * S + q * 4);
    const float4 bq = *reinterpret_cast<const float4*>(
        bins_g + (size_t)(h ? rayB : uray) * (S + 1) + q * 4);
    const float bLA = bins_g[(size_t)uray * (S + 1) + S];   // uniform s_loads
    const float bLB = bins_g[(size_t)rayB * (S + 1) + S];
    const float nA = nears[uray], nB = nears[rayB];
    const float fA = fars[uray],  fB = fars[rayB];

    const float w0 = wq.x + HPAD, w1 = wq.y + HPAD;
    const float w2 = wq.z + HPAD, w3 = wq.w + HPAD;
    const float s1 = w0, s2 = s1 + w1, s3 = s2 + w2, s4 = s3 + w3;

    // ---- dual 32-lane inclusive scan (DPP): ps = cumsum(s4) per half ----
    float ps = s4;
    ps = DPP_FADD(ps, 0x111, 0xf);  // row_shr:1
    ps = DPP_FADD(ps, 0x112, 0xf);  // row_shr:2
    ps = DPP_FADD(ps, 0x114, 0xf);  // row_shr:4
    ps = DPP_FADD(ps, 0x118, 0xf);  // row_shr:8
    ps = DPP_FADD(ps, 0x142, 0xa);  // row_bcast:15 -> rows 1,3 (32-lane scans)

    const float tA = __int_as_float(__builtin_amdgcn_readlane(__float_as_int(ps), 31));
    const float tB = __int_as_float(__builtin_amdgcn_readlane(__float_as_int(ps), 63));
    const float total = h ? tB : tA;

    const float padding = fmaxf(1e-5f - total, 0.0f);   // relu(EPS - w_sum)
    const float padc    = padding * (1.0f / S);
    const float inv     = __builtin_amdgcn_rcpf(total + padding);

    // ---- per-lane cdf edges (registers only); e[4] shared via shfl ----
    const float excl = ps - s4;                 // exclusive scan value
    const float g = (float)(4 * q);
    float e[5];
    e[4] = fminf(1.0f, fmaf(g + 4.0f, padc, ps) * inv);
    e[1] = fminf(1.0f, fmaf(g + 1.0f, padc, excl + s1) * inv);
    e[2] = fminf(1.0f, fmaf(g + 2.0f, padc, excl + s2) * inv);
    e[3] = fminf(1.0f, fmaf(g + 3.0f, padc, excl + s3) * inv);
    const float elo = __shfl_up(e[4], 1, 32);   // lane q-1's top edge (exact)
    e[0] = (q == 0) ? 0.0f : elo;               // cdf[0] = 0

    float bb[5];
    bb[0] = bq.x; bb[1] = bq.y; bb[2] = bq.z; bb[3] = bq.w;
    const float bn = __shfl_down(bq.x, 1, 32);  // next lane's first bin
    bb[4] = (q == 31) ? (h ? bLB : bLA) : bn;   // bins[128]

    const float nearv = h ? nB : nA;
    const float fmn   = (h ? fB : fA) - nearv;

    // first query index j with u_j >= c  (u_j = (2j+1)/130)
    auto jf = [](float c) -> int {
        int j = (int)ceilf(fmaf(65.0f, c, -0.5f));
        return j < 0 ? 0 : (j > NB ? NB : j);
    };

    int J[5];
    J[0] = jf(e[0]);
    J[4] = (q == 31) ? NB : jf(e[4]);           // last segment: open top
    J[1] = jf(e[1]); J[2] = jf(e[2]); J[3] = jf(e[3]);
    J[1] = J[1] < J[0] ? J[0] : (J[1] > J[4] ? J[4] : J[1]);
    J[2] = J[2] < J[1] ? J[1] : (J[2] > J[4] ? J[4] : J[2]);
    J[3] = J[3] < J[2] ? J[2] : (J[3] > J[4] ? J[4] : J[3]);

    float4* const wp = &pay[wv][h][0];

#pragma unroll
    for (int i = 0; i < 4; ++i) {
        if (J[i + 1] > J[i]) {                  // nonempty segment
            const float r = __builtin_amdgcn_rcpf(e[i + 1] - e[i]); // inf if d==0
            const float4 v = make_float4(e[i], r,
                                         fmaf(bb[i], fmn, nearv),
                                         (bb[i + 1] - bb[i]) * fmn);
            for (int j = J[i]; j < J[i + 1]; ++j) wp[j] = v;  // ds_write_b128
        }
    }

    // same-wave scatter -> gather: drain DS queue (wave-private slice).
    asm volatile("s_waitcnt lgkmcnt(0)" ::: "memory");

    // ---- uniform epilogue: lane j computes output j of both rays ----
    const float u = (float)(2 * lane + 1) * (1.0f / 130.0f);
    {
        const float4 p  = pay[wv][0][lane];
        const float  tc = fminf(fmaxf((u - p.x) * p.y, 0.0f), 1.0f); // NaN->0
        out[(size_t)uray * NB + lane] = fmaf(tc, p.w, p.z);
    }
    if (haveB) {
        const float4 p  = pay[wv][1][lane];
        const float  tc = fminf(fmaxf((u - p.x) * p.y, 0.0f), 1.0f);
        out[(size_t)rayB * NB + lane] = fmaf(tc, p.w, p.z);
    }
    if (lane < 2 && (lane == 0 || haveB)) {     // outputs [ray][64]
        const float4 p  = pay[wv][lane][64];
        const float  tc = fminf(fmaxf((129.0f / 130.0f - p.x) * p.y, 0.0f), 1.0f);
        out[(size_t)(uray + lane) * NB + 64] = fmaf(tc, p.w, p.z);
    }
}

extern "C" void kernel_launch(void* const* d_in, const int* in_sizes, int n_in,
                              void* d_out, int out_size, void* d_ws, size_t ws_size,
                              hipStream_t stream) {
    const float* weights = (const float*)d_in[0];   // [R,128,1]
    const float* ebins   = (const float*)d_in[1];   // [R,129]
    const float* nears   = (const float*)d_in[2];   // [R,1]
    const float* fars    = (const float*)d_in[3];   // [R,1]
    float* out = (float*)d_out;                     // [R,65]
    const int R = in_sizes[0] / 128;
    const int blocks = (R + 7) / 8;                 // 8 rays per block (2/wave)
    hipLaunchKernelGGL(neus_sampler_kernel, dim3(blocks), dim3(256), 0, stream,
                       weights, ebins, nears, fars, out, R);
}

// Round 4
// 162.454 us; speedup vs baseline: 1.0075x; 1.0075x over previous
//
#include <hip/hip_runtime.h>

// NeuSSampler PDF importance resampling — v4: scatter-max + prefix-max
// segment inversion. NO divergent loops anywhere.
//
// One wave per ray, 4 waves/block (v2 grid). Lane l owns weight/bin pair
// (2l, 2l+1) -> segments 2l, 2l+1.
//
// v3 post-mortem: 2-rays/wave did NOT reduce per-ray VALU (190 vs 197) —
// the work is per-SEGMENT, not per-ray-fixed. v2's real reducible cost:
// divergent scatter loops (wave-max trips: ~50 VALU + ~60 DS + ~100
// SALU/branch cyc/wave). v4 replaces them with an output-parallel inversion:
//   - owner(j) = largest k with jf(cdf[k]) <= j   (== searchsorted_right-1,
//     since jf(c) <= j  <=>  c <= u_j)
//   - each segment does ONE atomicMax(&best[j_start(k)], k)  (ds_max_u32)
//   - 6-step DPP prefix-max scan over best[0..63] -> M_j per lane
//   - payloads {c_start, d, base, scale} at STATIC addrs (2x ds_write_b128)
//   - lane j: one ds_read_b128 at pay[M_j], interp, coalesced 256B store
// Empty segments lose the atomicMax automatically (larger k wins at equal
// j_start). Selected segment has cdf[k] <= u < cdf[k+1] modulo ulp wobble;
// d<=0 / t outside [0,1] handled by the same NaN-safe clamp as v1-v3
// (rcp(0)=inf -> t=inf/NaN -> fmaxf(NaN,0)=0 / fminf(inf,1)=1).
//
// LDS per wave: 128 float4 payloads (2KB) + 66 uint best[] (264B), all
// wave-private -> no barriers; same-wave DS ordering + lgkmcnt(0) drain.

#define DPP_FADD(x, ctrl, rmask)                                             \
    ((x) + __int_as_float(__builtin_amdgcn_update_dpp(                       \
               0, __float_as_int(x), (ctrl), (rmask), 0xf, true)))

#define DPP_UMAX(x, ctrl, rmask)                                             \
    (umax_((x), (unsigned)__builtin_amdgcn_update_dpp(                       \
               0, (int)(x), (ctrl), (rmask), 0xf, true)))

__device__ __forceinline__ unsigned umax_(unsigned a, unsigned b) {
    return a > b ? a : b;
}

__global__ __launch_bounds__(256) void neus_sampler_kernel(
    const float* __restrict__ weights,
    const float* __restrict__ bins_g,
    const float* __restrict__ nears,
    const float* __restrict__ fars,
    float* __restrict__ out,
    int R)
{
    constexpr int S  = 128;   // weights per ray
    constexpr int NB = 65;    // output samples per ray
    constexpr float HPAD = 1e-5f;

    __shared__ float4   pay[4][S];      // 8192 B, wave-private rows
    __shared__ unsigned best[4][66];    // 1056 B; slot 65 = dump for j_start==65

    const int lane = threadIdx.x & 63;
    const int wv   = threadIdx.x >> 6;
    const int ray  = blockIdx.x * 4 + wv;
    if (ray >= R) return;                       // wave-uniform (no barriers)
    const int uray = __builtin_amdgcn_readfirstlane(ray);  // SGPR base addrs

    // init best[0..65] = 0 (segment 0 is the valid default owner: j_start(0)=0)
    if (lane < 33)
        *reinterpret_cast<unsigned long long*>(&best[wv][2 * lane]) = 0ull;

    // ---- coalesced vector loads: 2 weights + 2 bin edges per lane ----
    const float2 wpair =
        reinterpret_cast<const float2*>(weights + (size_t)uray * S)[lane];
    const float* brow = bins_g + (size_t)uray * (S + 1);
    const float2 bpair = reinterpret_cast<const float2*>(brow)[lane];
    const float b_last = brow[S];               // uniform -> s_load

    const float w1 = wpair.y + HPAD;
    float ps = (wpair.x + HPAD) + w1;           // pair sum

    // ---- wave64 inclusive scan (DPP): ps = cumsum(w)[2l+1] ----
    ps = DPP_FADD(ps, 0x111, 0xf);  // row_shr:1
    ps = DPP_FADD(ps, 0x112, 0xf);  // row_shr:2
    ps = DPP_FADD(ps, 0x114, 0xf);  // row_shr:4
    ps = DPP_FADD(ps, 0x118, 0xf);  // row_shr:8
    ps = DPP_FADD(ps, 0x142, 0xa);  // row_bcast:15 -> rows 1,3
    ps = DPP_FADD(ps, 0x143, 0xc);  // row_bcast:31 -> rows 2,3

    const float total =
        __int_as_float(__builtin_amdgcn_readlane(__float_as_int(ps), 63));
    const float padding = fmaxf(1e-5f - total, 0.0f);   // relu(EPS - w_sum)
    const float padc    = padding * (1.0f / S);
    const float inv     = __builtin_amdgcn_rcpf(total + padding);

    // ---- per-lane cdf edges (registers only) ----
    const float c_hi  = fminf(1.0f, fmaf((float)(2 * lane + 2), padc, ps) * inv);
    const float c_mid = fminf(1.0f, fmaf((float)(2 * lane + 1), padc, ps - w1) * inv);
    float c_lo = __shfl_up(c_hi, 1, 64);
    if (lane == 0) c_lo = 0.0f;                 // cdf[0]
    float b2 = __shfl_down(bpair.x, 1, 64);     // bins[2l+2]
    if (lane == 63) b2 = b_last;                // bins[128]

    const float nearv = nears[uray];            // uniform -> s_load
    const float farv  = fars[uray];
    const float fmn   = farv - nearv;

    // ---- payloads at static addresses (no divergence) ----
    pay[wv][2 * lane] = make_float4(
        c_lo, c_mid - c_lo, fmaf(bpair.x, fmn, nearv), (bpair.y - bpair.x) * fmn);
    pay[wv][2 * lane + 1] = make_float4(
        c_mid, c_hi - c_mid, fmaf(bpair.y, fmn, nearv), (b2 - bpair.y) * fmn);

    // first query index j with u_j >= c  (u_j = (2j+1)/130)
    auto jf = [](float c) -> int {
        int j = (int)ceilf(fmaf(65.0f, c, -0.5f));
        return j < 0 ? 0 : (j > NB ? NB : j);
    };

    // ---- scatter-max: one ds_max_u32 per segment, no loops ----
    atomicMax(&best[wv][jf(c_lo)],  (unsigned)(2 * lane));
    atomicMax(&best[wv][jf(c_mid)], (unsigned)(2 * lane + 1));

    // same-wave DS ordering; drain before reading back.
    asm volatile("s_waitcnt lgkmcnt(0)" ::: "memory");

    // ---- prefix-max scan: M_j = max(best[0..j]) = owner segment of slot j --
    unsigned m = best[wv][lane];
    m = DPP_UMAX(m, 0x111, 0xf);  // row_shr:1   (identity 0 for masked lanes)
    m = DPP_UMAX(m, 0x112, 0xf);  // row_shr:2
    m = DPP_UMAX(m, 0x114, 0xf);  // row_shr:4
    m = DPP_UMAX(m, 0x118, 0xf);  // row_shr:8
    m = DPP_UMAX(m, 0x142, 0xa);  // row_bcast:15
    m = DPP_UMAX(m, 0x143, 0xc);  // row_bcast:31

    // ---- uniform epilogue: lane j computes output j, coalesced store ----
    float* const orow = out + (size_t)uray * NB;
    {
        const float4 p  = pay[wv][m];
        const float  u  = (float)(2 * lane + 1) * (1.0f / 130.0f);
        const float  t  = (u - p.x) * __builtin_amdgcn_rcpf(p.y);
        const float  tc = fminf(fmaxf(t, 0.0f), 1.0f);  // NaN-safe: ->0
        orow[lane] = fmaf(tc, p.w, p.z);
    }
    if (lane == 63) {                                   // output 64
        const unsigned m64 = umax_(m, best[wv][64]);
        const float4 p  = pay[wv][m64];
        const float  t  = (129.0f / 130.0f - p.x) * __builtin_amdgcn_rcpf(p.y);
        const float  tc = fminf(fmaxf(t, 0.0f), 1.0f);
        orow[64] = fmaf(tc, p.w, p.z);
    }
}

extern "C" void kernel_launch(void* const* d_in, const int* in_sizes, int n_in,
                              void* d_out, int out_size, void* d_ws, size_t ws_size,
                              hipStream_t stream) {
    const float* weights = (const float*)d_in[0];   // [R,128,1]
    const float* ebins   = (const float*)d_in[1];   // [R,129]
    const float* nears   = (const float*)d_in[2];   // [R,1]
    const float* fars    = (const float*)d_in[3];   // [R,1]
    float* out = (float*)d_out;                     // [R,65]
    const int R = in_sizes[0] / 128;
    const int blocks = (R + 3) / 4;                 // 4 rays (waves) per block
    hipLaunchKernelGGL(neus_sampler_kernel, dim3(blocks), dim3(256), 0, stream,
                       weights, ebins, nears, fars, out, R);
}